// Round 8
// baseline (631.469 us; speedup 1.0000x reference)
//
#include <hip/hip_runtime.h>
#include <hip/hip_bf16.h>

// T=256, B=4096, H=64.
// k1m : root MLP fully on MFMA (unchanged; verified absmax 2.4e-4).
// k2m : 256 blocks x 640 threads = TWO independent 8-elem LSTM groups per block
//       (10 waves/CU) -> cross-group TLP fills the serial-chain stalls that
//       pinned R4/R7 at ~1.3 us/step. Per group: 4 gate waves + 1 critic wave,
//       register weight fragments, done flags in LDS, double-buffered hT2,
//       one block-wide barrier per step. MFMA rows 8-15 duplicate 0-7 (&7).

#define TT 256
#define BB 4096
#define TBROWS (TT * BB)
#define LOG2E 1.44269504088896340736f

typedef short bf16x8 __attribute__((ext_vector_type(8)));
typedef float f32x4 __attribute__((ext_vector_type(4)));

__device__ __forceinline__ unsigned bfbits(float x) {  // f32 -> bf16 bits, RTNE
  unsigned u = __float_as_uint(x);
  return (u + 0x7fffu + ((u >> 16) & 1u)) >> 16;
}
__device__ __forceinline__ unsigned pkbf(float lo, float hi) {
  return bfbits(lo) | (bfbits(hi) << 16);
}
__device__ __forceinline__ float rcpf_(float x) { return __builtin_amdgcn_rcpf(x); }
__device__ __forceinline__ float exp2f_(float x) { return __builtin_amdgcn_exp2f(x); }

// ---------------- k1m: MFMA root MLP -> bf16 hid (unchanged from R5) ----------------
__global__ __launch_bounds__(256) void k1m(const float* __restrict__ x,
                                           const float* __restrict__ Wr1,
                                           const float* __restrict__ br1,
                                           const float* __restrict__ Wr2,
                                           const float* __restrict__ br2,
                                           unsigned short* __restrict__ hb) {
  __shared__ int sBr1[2 * 256];
  __shared__ int sBr2[4 * 256];
  __shared__ float sx[4][208];
  __shared__ int h1s[4][324];

  const int tid = threadIdx.x;
  const int lane = tid & 63, wid = tid >> 6;
  const int g4 = lane >> 4, l15 = lane & 15;

  for (int i = tid; i < 512; i += 256) {
    int nt = i >> 8, rem = i & 255;
    int L = rem >> 2, d = rem & 3;
    int u = nt * 16 + (L & 15);
    int k0 = (L >> 4) * 4 + d;
    float v0 = (k0 < 9) ? Wr1[k0 * 32 + u] : 0.f;
    sBr1[i] = (int)bfbits(v0);
  }
  for (int i = tid; i < 1024; i += 256) {
    int nt = i >> 8, rem = i & 255;
    int L = rem >> 2, d = rem & 3;
    int u = nt * 16 + (L & 15);
    int p = (L >> 4) * 4 + d;
    sBr2[i] = (int)pkbf(Wr2[p * 64 + u], Wr2[(p + 16) * 64 + u]);
  }
  __syncthreads();

  float br1v[2] = {br1[l15], br1[16 + l15]};
  float br2v[4];
#pragma unroll
  for (int nt = 0; nt < 4; ++nt) br2v[nt] = br2[nt * 16 + l15];

  long gw = (long)blockIdx.x * 4 + wid;
  long nw = (long)gridDim.x * 4;
  for (long row0 = gw * 16; row0 < TBROWS; row0 += nw * 16) {
    {
      int j = lane;
      float v = x[row0 * 9 + j];
      int r = (j * 456) >> 12; int cc = j - r * 9;
      sx[wid][r * 12 + cc] = v;
      j = lane + 64;
      v = x[row0 * 9 + j];
      r = (j * 456) >> 12; cc = j - r * 9;
      sx[wid][r * 12 + cc] = v;
      if (lane < 16) {
        j = lane + 128;
        v = x[row0 * 9 + j];
        r = (j * 456) >> 12; cc = j - r * 9;
        sx[wid][r * 12 + cc] = v;
      }
    }
    float4 xq = *(const float4*)&sx[wid][l15 * 12 + g4 * 4];
    union { unsigned u[4]; bf16x8 v; } A1;
#pragma unroll
    for (int d = 0; d < 4; ++d) {
      float v = ((const float*)&xq)[d];
      v = (g4 * 4 + d < 9) ? v : 0.f;
      A1.u[d] = bfbits(v);
    }
    f32x4 c1[2];
#pragma unroll
    for (int nt = 0; nt < 2; ++nt) {
      c1[nt] = (f32x4){br1v[nt], br1v[nt], br1v[nt], br1v[nt]};
      c1[nt] = __builtin_amdgcn_mfma_f32_16x16x32_bf16(
          A1.v, *(const bf16x8*)&sBr1[nt * 256 + lane * 4], c1[nt], 0, 0, 0);
    }
#pragma unroll
    for (int r = 0; r < 4; ++r)
      h1s[wid][(g4 * 4 + r) * 20 + l15] =
          (int)pkbf(fmaxf(c1[0][r], 0.f), fmaxf(c1[1][r], 0.f));
    bf16x8 A2 = *(const bf16x8*)&h1s[wid][l15 * 20 + g4 * 4];
    f32x4 c2[4];
#pragma unroll
    for (int nt = 0; nt < 4; ++nt) {
      c2[nt] = (f32x4){br2v[nt], br2v[nt], br2v[nt], br2v[nt]};
      c2[nt] = __builtin_amdgcn_mfma_f32_16x16x32_bf16(
          A2, *(const bf16x8*)&sBr2[nt * 256 + lane * 4], c2[nt], 0, 0, 0);
    }
#pragma unroll
    for (int nt = 0; nt < 4; ++nt)
#pragma unroll
      for (int r = 0; r < 4; ++r)
        hb[(row0 + g4 * 4 + r) * 64 + nt * 16 + l15] =
            (unsigned short)bfbits(fmaxf(c2[nt][r], 0.f));
  }
}

// ---------------- k2m: MFMA serial LSTM, 2 groups x (4 gate + 1 critic) waves ----------------
// C layout (m89): col = lane&15, row = (lane>>4)*4 + reg.
// Gate wave w of a group: nt = g*4+w -> unit j = 16w + (lane&15), gate g.
__global__ __launch_bounds__(640) void k2m(
    const unsigned short* __restrict__ hb, const int* __restrict__ done,
    const float* __restrict__ h0, const float* __restrict__ c0,
    const float* __restrict__ Wih, const float* __restrict__ Whh,
    const float* __restrict__ bl,
    const float* __restrict__ Wc1, const float* __restrict__ bc1,
    const float* __restrict__ Wc2, const float* __restrict__ bc2,
    const float* __restrict__ Wc3, const float* __restrict__ bc3,
    float* __restrict__ out) {
  __shared__ __align__(16) unsigned short hT2[2][2][16 * 72];  // [grp][buf][elem*72]
  __shared__ float sv1[2][16 * 20];
  __shared__ int sdone[2][TT * 8];   // [grp][t*8+e]

  const int tid = threadIdx.x;
  const int grp = (tid >= 320) ? 1 : 0;
  const int gt = tid - grp * 320;
  const int lane = gt & 63;
  const int wid = gt >> 6;           // 0..4 within group
  const int g4 = lane >> 4, l15 = lane & 15;
  const int base_b = blockIdx.x * 16 + grp * 8;

  // ---- preload done flags (once) ----
  for (int i = gt; i < TT * 8; i += 320)
    sdone[grp][i] = done[(long)(i >> 3) * BB + base_b + (i & 7)];

  // ---- per-wave register weight fragments ----
  union frag { unsigned u[4]; bf16x8 v; };
  frag Bih[4][2], Bhh[4][2];
  frag Bc1[2];
  float wc2a[16], wc2b[16];
  float c[4], bias_g[4];
  float bc1s = 0.f, bc2s0 = 0.f, bc2s1 = 0.f, wc3a = 0.f, wc3b = 0.f, bc3r = 0.f;

  if (wid < 4) {
#pragma unroll
    for (int g = 0; g < 4; ++g) {
      int nt = g * 4 + wid;
      int col = nt * 16 + l15;
      float sc = (g == 2) ? 2.f * LOG2E : LOG2E;
#pragma unroll
      for (int q = 0; q < 2; ++q)
#pragma unroll
        for (int d = 0; d < 4; ++d) {
          int k0 = q * 32 + g4 * 8 + 2 * d;
          Bih[g][q].u[d] = pkbf(Wih[k0 * 256 + col] * sc, Wih[(k0 + 1) * 256 + col] * sc);
          Bhh[g][q].u[d] = pkbf(Whh[k0 * 256 + col] * sc, Whh[(k0 + 1) * 256 + col] * sc);
        }
      bias_g[g] = bl[nt * 16 + l15] * sc;
    }
#pragma unroll
    for (int r = 0; r < 4; ++r) {
      int row = base_b + ((g4 * 4 + r) & 7);   // rows 8-15 duplicate 0-7
      float m0 = 1.f - (float)done[row];
      c[r] = c0[row * 64 + wid * 16 + l15] * m0;
      hT2[grp][1][(g4 * 4 + r) * 72 + wid * 16 + l15] =
          (unsigned short)bfbits(h0[row * 64 + wid * 16 + l15]);
    }
  } else {
    float S = 2.f * LOG2E;
#pragma unroll
    for (int q = 0; q < 2; ++q)
#pragma unroll
      for (int d = 0; d < 4; ++d) {
        int k0 = q * 32 + g4 * 8 + 2 * d;
        Bc1[q].u[d] = pkbf(Wc1[k0 * 16 + l15] * S, Wc1[(k0 + 1) * 16 + l15] * S);
      }
#pragma unroll
    for (int k = 0; k < 16; ++k) {
      wc2a[k] = Wc2[k * 8 + g4 * 2] * S;
      wc2b[k] = Wc2[k * 8 + g4 * 2 + 1] * S;
    }
    bc1s = bc1[l15] * S;
    bc2s0 = bc2[g4 * 2] * S;
    bc2s1 = bc2[g4 * 2 + 1] * S;
    wc3a = Wc3[g4 * 2];
    wc3b = Wc3[g4 * 2 + 1];
    bc3r = bc3[0];
  }
  __syncthreads();

  bf16x8 aih0 = {}, aih1 = {};
  if (wid < 4) {
    long rowA = base_b + (l15 & 7);
    aih0 = *(const bf16x8*)(hb + rowA * 64 + g4 * 8);
    aih1 = *(const bf16x8*)(hb + rowA * 64 + 32 + g4 * 8);
  }

  auto critic_step = [&](int tprev, const unsigned short* rb) {
    bf16x8 ca0 = *(const bf16x8*)(rb + l15 * 72 + g4 * 8);
    bf16x8 ca1 = *(const bf16x8*)(rb + l15 * 72 + 32 + g4 * 8);
    f32x4 a1 = (f32x4){bc1s, bc1s, bc1s, bc1s};
    a1 = __builtin_amdgcn_mfma_f32_16x16x32_bf16(ca0, Bc1[0].v, a1, 0, 0, 0);
    a1 = __builtin_amdgcn_mfma_f32_16x16x32_bf16(ca1, Bc1[1].v, a1, 0, 0, 0);
#pragma unroll
    for (int r = 0; r < 4; ++r) {
      float v1 = fmaf(2.f, rcpf_(1.f + exp2f_(-a1[r])), -1.f);
      sv1[grp][(g4 * 4 + r) * 20 + l15] = v1;
    }
    float a2a = bc2s0, a2b = bc2s1;
    const float* vrow = &sv1[grp][l15 * 20];
#pragma unroll
    for (int k = 0; k < 16; ++k) {
      float vk = vrow[k];
      a2a = fmaf(vk, wc2a[k], a2a);
      a2b = fmaf(vk, wc2b[k], a2b);
    }
    float v2a = fmaf(2.f, rcpf_(1.f + exp2f_(-a2a)), -1.f);
    float v2b = fmaf(2.f, rcpf_(1.f + exp2f_(-a2b)), -1.f);
    float p = fmaf(v2a, wc3a, v2b * wc3b);
    p += __shfl_xor(p, 16);
    p += __shfl_xor(p, 32);
    if (g4 == 0 && l15 < 8) out[(long)tprev * BB + base_b + l15] = p + bc3r;
  };

  for (int t = 0; t < TT; ++t) {
    const unsigned short* rb = hT2[grp][(t + 1) & 1];  // h_{t-1}
    unsigned short* wb = hT2[grp][t & 1];
    if (wid < 4) {
      // issue next-step global prefetch FIRST (wait sinks to step bottom)
      bf16x8 nx0 = aih0, nx1 = aih1;
      if (t + 1 < TT) {
        long nb = ((long)(t + 1) * BB + base_b + (l15 & 7)) * 64;
        nx0 = *(const bf16x8*)(hb + nb + g4 * 8);
        nx1 = *(const bf16x8*)(hb + nb + 32 + g4 * 8);
      }
      // A_hh from LDS, masked by done[t]
      int dn = sdone[grp][t * 8 + (l15 & 7)];
      int4 r0 = *(const int4*)(rb + l15 * 72 + g4 * 8);
      int4 r1 = *(const int4*)(rb + l15 * 72 + 32 + g4 * 8);
      if (dn != 0) { r0 = make_int4(0, 0, 0, 0); r1 = make_int4(0, 0, 0, 0); }
      union { int4 i4; bf16x8 v; } ah0, ah1;
      ah0.i4 = r0; ah1.i4 = r1;

      f32x4 accP[4], accQ[4];
#pragma unroll
      for (int g = 0; g < 4; ++g) {
        accP[g] = (f32x4){bias_g[g], bias_g[g], bias_g[g], bias_g[g]};
        accQ[g] = (f32x4){0.f, 0.f, 0.f, 0.f};
      }
#pragma unroll
      for (int g = 0; g < 4; ++g) {
        accP[g] = __builtin_amdgcn_mfma_f32_16x16x32_bf16(aih0, Bih[g][0].v, accP[g], 0, 0, 0);
        accQ[g] = __builtin_amdgcn_mfma_f32_16x16x32_bf16(aih1, Bih[g][1].v, accQ[g], 0, 0, 0);
      }
#pragma unroll
      for (int g = 0; g < 4; ++g) {
        accP[g] = __builtin_amdgcn_mfma_f32_16x16x32_bf16(ah0.v, Bhh[g][0].v, accP[g], 0, 0, 0);
        accQ[g] = __builtin_amdgcn_mfma_f32_16x16x32_bf16(ah1.v, Bhh[g][1].v, accQ[g], 0, 0, 0);
      }

      float out_h[4];
#pragma unroll
      for (int r = 0; r < 4; ++r) {
        float xi = accP[0][r] + accQ[0][r];
        float xf = accP[1][r] + accQ[1][r];
        float xg = accP[2][r] + accQ[2][r];
        float xo = accP[3][r] + accQ[3][r];
        float si = rcpf_(1.f + exp2f_(-xi));
        float sf = rcpf_(1.f + exp2f_(-xf));
        float so = rcpf_(1.f + exp2f_(-xo));
        float tg = fmaf(2.f, rcpf_(1.f + exp2f_(-xg)), -1.f);
        float cc = fmaf(sf, c[r], si * tg);
        float tc = fmaf(2.f, rcpf_(1.f + exp2f_(cc * (-2.f * LOG2E))), -1.f);
        out_h[r] = so * tc;
        float mn = (t + 1 < TT) ? (1.f - (float)sdone[grp][(t + 1) * 8 + ((g4 * 4 + r) & 7)]) : 1.f;
        c[r] = cc * mn;  // mask for t+1
      }
#pragma unroll
      for (int r = 0; r < 4; ++r)
        wb[(g4 * 4 + r) * 72 + wid * 16 + l15] = (unsigned short)bfbits(out_h[r]);

      aih0 = nx0; aih1 = nx1;  // vmcnt wait lands here, ~full step of slack
    } else {
      if (t > 0) critic_step(t - 1, rb);
    }
    __syncthreads();  // one block-wide barrier per step (both groups)
  }
  if (wid == 4) critic_step(TT - 1, hT2[grp][(TT - 1) & 1]);
}

extern "C" void kernel_launch(void* const* d_in, const int* in_sizes, int n_in,
                              void* d_out, int out_size, void* d_ws, size_t ws_size,
                              hipStream_t stream) {
  const float* x = (const float*)d_in[0];
  const int* done = (const int*)d_in[1];
  const float* h0 = (const float*)d_in[2];
  const float* c0 = (const float*)d_in[3];
  const float* Wr1 = (const float*)d_in[4];
  const float* br1 = (const float*)d_in[5];
  const float* Wr2 = (const float*)d_in[6];
  const float* br2 = (const float*)d_in[7];
  const float* Wih = (const float*)d_in[8];
  const float* Whh = (const float*)d_in[9];
  const float* bl = (const float*)d_in[10];
  const float* Wc1 = (const float*)d_in[11];
  const float* bc1 = (const float*)d_in[12];
  const float* Wc2 = (const float*)d_in[13];
  const float* bc2 = (const float*)d_in[14];
  const float* Wc3 = (const float*)d_in[15];
  const float* bc3 = (const float*)d_in[16];
  float* out = (float*)d_out;

  unsigned short* hb = (unsigned short*)d_ws;  // 128 MB bf16 hid (read-only after k1m)

  k1m<<<dim3(1024), dim3(256), 0, stream>>>(x, Wr1, br1, Wr2, br2, hb);
  k2m<<<dim3(256), dim3(640), 0, stream>>>(hb, done, h0, c0, Wih, Whh, bl,
                                           Wc1, bc1, Wc2, bc2, Wc3, bc3, out);
}

// Round 9
// 228.459 us; speedup vs baseline: 2.7640x; 2.7640x over previous
//
#include <hip/hip_runtime.h>
#include <hip/hip_bf16.h>

// T=256, B=4096, H=64.
// k1m : root MLP fully on MFMA (unchanged; verified absmax 2.4e-4).
// k2m : R7 geometry (256 blocks x 16 elems, 4 gate waves + 1 critic wave,
//       register weights, sdone in LDS, double-buffered hT2) with the step
//       de-serialized:
//       - RAW s_barrier + lgkmcnt(0)-only wait (no vmcnt drain: kernel has no
//         intra-kernel global RAW, so HBM prefetches legally span barriers)
//       - manual x2 unroll, distance-2 in-place hb prefetch (vmcnt wait lands
//         ~2 steps after issue > 900cy HBM latency)
//       - done flags carried in registers (no LDS read on the critical chain)
//       - Whh MFMAs first (LDS-fed), Wih MFMAs second (prefetch-fed)

#define TT 256
#define BB 4096
#define TBROWS (TT * BB)
#define LOG2E 1.44269504088896340736f

typedef short bf16x8 __attribute__((ext_vector_type(8)));
typedef float f32x4 __attribute__((ext_vector_type(4)));

__device__ __forceinline__ unsigned bfbits(float x) {  // f32 -> bf16 bits, RTNE
  unsigned u = __float_as_uint(x);
  return (u + 0x7fffu + ((u >> 16) & 1u)) >> 16;
}
__device__ __forceinline__ unsigned pkbf(float lo, float hi) {
  return bfbits(lo) | (bfbits(hi) << 16);
}
__device__ __forceinline__ float rcpf_(float x) { return __builtin_amdgcn_rcpf(x); }
__device__ __forceinline__ float exp2f_(float x) { return __builtin_amdgcn_exp2f(x); }

// raw barrier: LDS-ordered only, compiler fenced, NO vmcnt drain
#define BAR_LDS()                                                   \
  do {                                                              \
    asm volatile("s_waitcnt lgkmcnt(0)" ::: "memory");              \
    __builtin_amdgcn_s_barrier();                                   \
    asm volatile("" ::: "memory");                                  \
  } while (0)

// ---------------- k1m: MFMA root MLP -> bf16 hid (unchanged from R5) ----------------
__global__ __launch_bounds__(256) void k1m(const float* __restrict__ x,
                                           const float* __restrict__ Wr1,
                                           const float* __restrict__ br1,
                                           const float* __restrict__ Wr2,
                                           const float* __restrict__ br2,
                                           unsigned short* __restrict__ hb) {
  __shared__ int sBr1[2 * 256];
  __shared__ int sBr2[4 * 256];
  __shared__ float sx[4][208];
  __shared__ int h1s[4][324];

  const int tid = threadIdx.x;
  const int lane = tid & 63, wid = tid >> 6;
  const int g4 = lane >> 4, l15 = lane & 15;

  for (int i = tid; i < 512; i += 256) {
    int nt = i >> 8, rem = i & 255;
    int L = rem >> 2, d = rem & 3;
    int u = nt * 16 + (L & 15);
    int k0 = (L >> 4) * 4 + d;
    float v0 = (k0 < 9) ? Wr1[k0 * 32 + u] : 0.f;
    sBr1[i] = (int)bfbits(v0);
  }
  for (int i = tid; i < 1024; i += 256) {
    int nt = i >> 8, rem = i & 255;
    int L = rem >> 2, d = rem & 3;
    int u = nt * 16 + (L & 15);
    int p = (L >> 4) * 4 + d;
    sBr2[i] = (int)pkbf(Wr2[p * 64 + u], Wr2[(p + 16) * 64 + u]);
  }
  __syncthreads();

  float br1v[2] = {br1[l15], br1[16 + l15]};
  float br2v[4];
#pragma unroll
  for (int nt = 0; nt < 4; ++nt) br2v[nt] = br2[nt * 16 + l15];

  long gw = (long)blockIdx.x * 4 + wid;
  long nw = (long)gridDim.x * 4;
  for (long row0 = gw * 16; row0 < TBROWS; row0 += nw * 16) {
    {
      int j = lane;
      float v = x[row0 * 9 + j];
      int r = (j * 456) >> 12; int cc = j - r * 9;
      sx[wid][r * 12 + cc] = v;
      j = lane + 64;
      v = x[row0 * 9 + j];
      r = (j * 456) >> 12; cc = j - r * 9;
      sx[wid][r * 12 + cc] = v;
      if (lane < 16) {
        j = lane + 128;
        v = x[row0 * 9 + j];
        r = (j * 456) >> 12; cc = j - r * 9;
        sx[wid][r * 12 + cc] = v;
      }
    }
    float4 xq = *(const float4*)&sx[wid][l15 * 12 + g4 * 4];
    union { unsigned u[4]; bf16x8 v; } A1;
#pragma unroll
    for (int d = 0; d < 4; ++d) {
      float v = ((const float*)&xq)[d];
      v = (g4 * 4 + d < 9) ? v : 0.f;
      A1.u[d] = bfbits(v);
    }
    f32x4 c1[2];
#pragma unroll
    for (int nt = 0; nt < 2; ++nt) {
      c1[nt] = (f32x4){br1v[nt], br1v[nt], br1v[nt], br1v[nt]};
      c1[nt] = __builtin_amdgcn_mfma_f32_16x16x32_bf16(
          A1.v, *(const bf16x8*)&sBr1[nt * 256 + lane * 4], c1[nt], 0, 0, 0);
    }
#pragma unroll
    for (int r = 0; r < 4; ++r)
      h1s[wid][(g4 * 4 + r) * 20 + l15] =
          (int)pkbf(fmaxf(c1[0][r], 0.f), fmaxf(c1[1][r], 0.f));
    bf16x8 A2 = *(const bf16x8*)&h1s[wid][l15 * 20 + g4 * 4];
    f32x4 c2[4];
#pragma unroll
    for (int nt = 0; nt < 4; ++nt) {
      c2[nt] = (f32x4){br2v[nt], br2v[nt], br2v[nt], br2v[nt]};
      c2[nt] = __builtin_amdgcn_mfma_f32_16x16x32_bf16(
          A2, *(const bf16x8*)&sBr2[nt * 256 + lane * 4], c2[nt], 0, 0, 0);
    }
#pragma unroll
    for (int nt = 0; nt < 4; ++nt)
#pragma unroll
      for (int r = 0; r < 4; ++r)
        hb[(row0 + g4 * 4 + r) * 64 + nt * 16 + l15] =
            (unsigned short)bfbits(fmaxf(c2[nt][r], 0.f));
  }
}

// ---------------- k2m: MFMA serial LSTM, raw barriers + dist-2 prefetch ----------------
// C layout (m89): col = lane&15, row = (lane>>4)*4 + reg.
// Gate wave w: nt = g*4+w -> unit j = 16w + (lane&15), gate g.
__global__ __launch_bounds__(320) void k2m(
    const unsigned short* __restrict__ hb, const int* __restrict__ done,
    const float* __restrict__ h0, const float* __restrict__ c0,
    const float* __restrict__ Wih, const float* __restrict__ Whh,
    const float* __restrict__ bl,
    const float* __restrict__ Wc1, const float* __restrict__ bc1,
    const float* __restrict__ Wc2, const float* __restrict__ bc2,
    const float* __restrict__ Wc3, const float* __restrict__ bc3,
    float* __restrict__ out) {
  __shared__ __align__(16) unsigned short hT2[2][16 * 72];  // double-buffered h (unmasked)
  __shared__ float sv1[16 * 20];                            // critic v1 bounce
  __shared__ int sdone[TT * 16];                            // done flags (16 KB)

  const int tid = threadIdx.x;
  const int lane = tid & 63;
  const int wid = tid >> 6;
  const int g4 = lane >> 4, l15 = lane & 15;
  const int base_b = blockIdx.x * 16;

  for (int i = tid; i < TT * 16; i += 320)
    sdone[i] = done[(long)(i >> 4) * BB + base_b + (i & 15)];

  union frag { unsigned u[4]; bf16x8 v; };
  frag Bih[4][2], Bhh[4][2];
  frag Bc1[2];
  float wc2a[16], wc2b[16];
  float c[4], bias_g[4];
  float bc1s = 0.f, bc2s0 = 0.f, bc2s1 = 0.f, wc3a = 0.f, wc3b = 0.f, bc3r = 0.f;

  if (wid < 4) {
#pragma unroll
    for (int g = 0; g < 4; ++g) {
      int nt = g * 4 + wid;
      int col = nt * 16 + l15;
      float sc = (g == 2) ? 2.f * LOG2E : LOG2E;
#pragma unroll
      for (int q = 0; q < 2; ++q)
#pragma unroll
        for (int d = 0; d < 4; ++d) {
          int k0 = q * 32 + g4 * 8 + 2 * d;
          Bih[g][q].u[d] = pkbf(Wih[k0 * 256 + col] * sc, Wih[(k0 + 1) * 256 + col] * sc);
          Bhh[g][q].u[d] = pkbf(Whh[k0 * 256 + col] * sc, Whh[(k0 + 1) * 256 + col] * sc);
        }
      bias_g[g] = bl[nt * 16 + l15] * sc;
    }
#pragma unroll
    for (int r = 0; r < 4; ++r) {
      int row = base_b + g4 * 4 + r;
      float m0 = 1.f - (float)done[row];
      c[r] = c0[row * 64 + wid * 16 + l15] * m0;
      hT2[1][(g4 * 4 + r) * 72 + wid * 16 + l15] =
          (unsigned short)bfbits(h0[row * 64 + wid * 16 + l15]);
    }
  } else {
    float S = 2.f * LOG2E;
#pragma unroll
    for (int q = 0; q < 2; ++q)
#pragma unroll
      for (int d = 0; d < 4; ++d) {
        int k0 = q * 32 + g4 * 8 + 2 * d;
        Bc1[q].u[d] = pkbf(Wc1[k0 * 16 + l15] * S, Wc1[(k0 + 1) * 16 + l15] * S);
      }
#pragma unroll
    for (int k = 0; k < 16; ++k) {
      wc2a[k] = Wc2[k * 8 + g4 * 2] * S;
      wc2b[k] = Wc2[k * 8 + g4 * 2 + 1] * S;
    }
    bc1s = bc1[l15] * S;
    bc2s0 = bc2[g4 * 2] * S;
    bc2s1 = bc2[g4 * 2 + 1] * S;
    wc3a = Wc3[g4 * 2];
    wc3b = Wc3[g4 * 2 + 1];
    bc3r = bc3[0];
  }
  __syncthreads();  // full barrier once (setup visibility)

  // gate-wave loop state: dist-2 prefetch registers (in-place reload, no copies)
  bf16x8 aA0 = {}, aA1 = {}, aB0 = {}, aB1 = {};
  int dnA = 0, dnB = 0;
  if (wid < 4) {
    long r0a = ((long)0 * BB + base_b + l15) * 64;
    long r1a = ((long)1 * BB + base_b + l15) * 64;
    aA0 = *(const bf16x8*)(hb + r0a + g4 * 8);
    aA1 = *(const bf16x8*)(hb + r0a + 32 + g4 * 8);
    aB0 = *(const bf16x8*)(hb + r1a + g4 * 8);
    aB1 = *(const bf16x8*)(hb + r1a + 32 + g4 * 8);
    dnA = sdone[0 * 16 + l15];
    dnB = sdone[1 * 16 + l15];
  }

  auto gate_step = [&](int t, bf16x8& x0, bf16x8& x1, int& dnv) {
    const unsigned short* rb = hT2[(t + 1) & 1];  // h_{t-1}
    unsigned short* wb = hT2[t & 1];
    // hot chain: LDS read -> cndmask -> MFMA
    int4 r0 = *(const int4*)(rb + l15 * 72 + g4 * 8);
    int4 r1 = *(const int4*)(rb + l15 * 72 + 32 + g4 * 8);
    if (dnv != 0) { r0 = make_int4(0, 0, 0, 0); r1 = make_int4(0, 0, 0, 0); }
    union { int4 i4; bf16x8 v; } ah0, ah1;
    ah0.i4 = r0; ah1.i4 = r1;

    f32x4 accP[4], accQ[4];
#pragma unroll
    for (int g = 0; g < 4; ++g) {
      accP[g] = (f32x4){bias_g[g], bias_g[g], bias_g[g], bias_g[g]};
      accQ[g] = (f32x4){0.f, 0.f, 0.f, 0.f};
    }
    // Whh first (LDS-fed), Wih second (prefetch-fed; vmcnt wait lands here)
#pragma unroll
    for (int g = 0; g < 4; ++g) {
      accP[g] = __builtin_amdgcn_mfma_f32_16x16x32_bf16(ah0.v, Bhh[g][0].v, accP[g], 0, 0, 0);
      accQ[g] = __builtin_amdgcn_mfma_f32_16x16x32_bf16(ah1.v, Bhh[g][1].v, accQ[g], 0, 0, 0);
    }
#pragma unroll
    for (int g = 0; g < 4; ++g) {
      accP[g] = __builtin_amdgcn_mfma_f32_16x16x32_bf16(x0, Bih[g][0].v, accP[g], 0, 0, 0);
      accQ[g] = __builtin_amdgcn_mfma_f32_16x16x32_bf16(x1, Bih[g][1].v, accQ[g], 0, 0, 0);
    }
    // in-place dist-2 reload (issue now, wait ~2 steps later)
    if (t + 2 < TT) {
      long nb = ((long)(t + 2) * BB + base_b + l15) * 64;
      x0 = *(const bf16x8*)(hb + nb + g4 * 8);
      x1 = *(const bf16x8*)(hb + nb + 32 + g4 * 8);
      dnv = sdone[(t + 2) * 16 + l15];
    }

    float out_h[4];
#pragma unroll
    for (int r = 0; r < 4; ++r) {
      float xi = accP[0][r] + accQ[0][r];
      float xf = accP[1][r] + accQ[1][r];
      float xg = accP[2][r] + accQ[2][r];
      float xo = accP[3][r] + accQ[3][r];
      float si = rcpf_(1.f + exp2f_(-xi));
      float sf = rcpf_(1.f + exp2f_(-xf));
      float so = rcpf_(1.f + exp2f_(-xo));
      float tg = fmaf(2.f, rcpf_(1.f + exp2f_(-xg)), -1.f);
      float cc = fmaf(sf, c[r], si * tg);
      float tc = fmaf(2.f, rcpf_(1.f + exp2f_(cc * (-2.f * LOG2E))), -1.f);
      out_h[r] = so * tc;
      float mn = (t + 1 < TT) ? (1.f - (float)sdone[(t + 1) * 16 + g4 * 4 + r]) : 1.f;
      c[r] = cc * mn;  // mask for t+1
    }
#pragma unroll
    for (int r = 0; r < 4; ++r)
      wb[(g4 * 4 + r) * 72 + wid * 16 + l15] = (unsigned short)bfbits(out_h[r]);
  };

  auto critic_step = [&](int tprev, const unsigned short* rb) {
    bf16x8 ca0 = *(const bf16x8*)(rb + l15 * 72 + g4 * 8);
    bf16x8 ca1 = *(const bf16x8*)(rb + l15 * 72 + 32 + g4 * 8);
    f32x4 a1 = (f32x4){bc1s, bc1s, bc1s, bc1s};
    a1 = __builtin_amdgcn_mfma_f32_16x16x32_bf16(ca0, Bc1[0].v, a1, 0, 0, 0);
    a1 = __builtin_amdgcn_mfma_f32_16x16x32_bf16(ca1, Bc1[1].v, a1, 0, 0, 0);
#pragma unroll
    for (int r = 0; r < 4; ++r) {
      float v1 = fmaf(2.f, rcpf_(1.f + exp2f_(-a1[r])), -1.f);
      sv1[(g4 * 4 + r) * 20 + l15] = v1;
    }
    float a2a = bc2s0, a2b = bc2s1;
    const float* vrow = &sv1[l15 * 20];
#pragma unroll
    for (int k = 0; k < 16; ++k) {
      float vk = vrow[k];
      a2a = fmaf(vk, wc2a[k], a2a);
      a2b = fmaf(vk, wc2b[k], a2b);
    }
    float v2a = fmaf(2.f, rcpf_(1.f + exp2f_(-a2a)), -1.f);
    float v2b = fmaf(2.f, rcpf_(1.f + exp2f_(-a2b)), -1.f);
    float p = fmaf(v2a, wc3a, v2b * wc3b);
    p += __shfl_xor(p, 16);
    p += __shfl_xor(p, 32);
    if (g4 == 0) out[(long)tprev * BB + base_b + l15] = p + bc3r;
  };

  for (int t2 = 0; t2 < TT; t2 += 2) {
    // ---- even sub-step t = t2 ----
    if (wid < 4) {
      gate_step(t2, aA0, aA1, dnA);
    } else {
      if (t2 > 0) critic_step(t2 - 1, hT2[(t2 + 1) & 1]);
    }
    BAR_LDS();
    // ---- odd sub-step t = t2+1 ----
    if (wid < 4) {
      gate_step(t2 + 1, aB0, aB1, dnB);
    } else {
      critic_step(t2, hT2[(t2 + 2) & 1]);
    }
    BAR_LDS();
  }
  if (wid == 4) critic_step(TT - 1, hT2[(TT - 1) & 1]);
}

extern "C" void kernel_launch(void* const* d_in, const int* in_sizes, int n_in,
                              void* d_out, int out_size, void* d_ws, size_t ws_size,
                              hipStream_t stream) {
  const float* x = (const float*)d_in[0];
  const int* done = (const int*)d_in[1];
  const float* h0 = (const float*)d_in[2];
  const float* c0 = (const float*)d_in[3];
  const float* Wr1 = (const float*)d_in[4];
  const float* br1 = (const float*)d_in[5];
  const float* Wr2 = (const float*)d_in[6];
  const float* br2 = (const float*)d_in[7];
  const float* Wih = (const float*)d_in[8];
  const float* Whh = (const float*)d_in[9];
  const float* bl = (const float*)d_in[10];
  const float* Wc1 = (const float*)d_in[11];
  const float* bc1 = (const float*)d_in[12];
  const float* Wc2 = (const float*)d_in[13];
  const float* bc2 = (const float*)d_in[14];
  const float* Wc3 = (const float*)d_in[15];
  const float* bc3 = (const float*)d_in[16];
  float* out = (float*)d_out;

  unsigned short* hb = (unsigned short*)d_ws;  // 128 MB bf16 hid (read-only after k1m)

  k1m<<<dim3(1024), dim3(256), 0, stream>>>(x, Wr1, br1, Wr2, br2, hb);
  k2m<<<dim3(256), dim3(320), 0, stream>>>(hb, done, h0, c0, Wih, Whh, bl,
                                           Wc1, bc1, Wc2, bc2, Wc3, bc3, out);
}

// Round 10
// 197.454 us; speedup vs baseline: 3.1980x; 1.1570x over previous
//
#include <hip/hip_runtime.h>
#include <hip/hip_bf16.h>

// T=256, B=4096, H=64.
// k1m : root MLP fully on MFMA (unchanged; verified absmax 2.4e-4).
// k2m : R9 structure (256 blocks x 16 elems, 4 gate + 1 critic wave, register
//       weights, raw s_barrier + lgkmcnt-only wait, dist-2 hb prefetch) with
//       the per-step instruction stream tightened:
//       - ds_read hT2 issued first; Wih MFMAs (h-independent) fill LDS latency
//       - single 4-deep MFMA chain per gate, C-input = persistent bias regs
//       - done-mask as float4 in LDS (no per-step cvt), dn flag dist-2 in reg
//       - bf16 pack via v_cvt_pk_bf16_f32
//       - s_setprio(1) around the gate hot region

#define TT 256
#define BB 4096
#define TBROWS (TT * BB)
#define LOG2E 1.44269504088896340736f

typedef short bf16x8 __attribute__((ext_vector_type(8)));
typedef float f32x4 __attribute__((ext_vector_type(4)));

__device__ __forceinline__ unsigned bfbits(float x) {  // f32 -> bf16 bits, RTNE
  unsigned u = __float_as_uint(x);
  return (u + 0x7fffu + ((u >> 16) & 1u)) >> 16;
}
__device__ __forceinline__ unsigned pkbf(float lo, float hi) {
  return bfbits(lo) | (bfbits(hi) << 16);
}
__device__ __forceinline__ unsigned short cvt1bf(float x) {
  unsigned pk;
  asm("v_cvt_pk_bf16_f32 %0, %1, %2" : "=v"(pk) : "v"(x), "v"(x));
  return (unsigned short)pk;
}
__device__ __forceinline__ float rcpf_(float x) { return __builtin_amdgcn_rcpf(x); }
__device__ __forceinline__ float exp2f_(float x) { return __builtin_amdgcn_exp2f(x); }

// raw barrier: LDS-ordered only, compiler fenced, NO vmcnt drain
#define BAR_LDS()                                                   \
  do {                                                              \
    asm volatile("s_waitcnt lgkmcnt(0)" ::: "memory");              \
    __builtin_amdgcn_s_barrier();                                   \
    asm volatile("" ::: "memory");                                  \
  } while (0)

// ---------------- k1m: MFMA root MLP -> bf16 hid (unchanged from R5) ----------------
__global__ __launch_bounds__(256) void k1m(const float* __restrict__ x,
                                           const float* __restrict__ Wr1,
                                           const float* __restrict__ br1,
                                           const float* __restrict__ Wr2,
                                           const float* __restrict__ br2,
                                           unsigned short* __restrict__ hb) {
  __shared__ int sBr1[2 * 256];
  __shared__ int sBr2[4 * 256];
  __shared__ float sx[4][208];
  __shared__ int h1s[4][324];

  const int tid = threadIdx.x;
  const int lane = tid & 63, wid = tid >> 6;
  const int g4 = lane >> 4, l15 = lane & 15;

  for (int i = tid; i < 512; i += 256) {
    int nt = i >> 8, rem = i & 255;
    int L = rem >> 2, d = rem & 3;
    int u = nt * 16 + (L & 15);
    int k0 = (L >> 4) * 4 + d;
    float v0 = (k0 < 9) ? Wr1[k0 * 32 + u] : 0.f;
    sBr1[i] = (int)bfbits(v0);
  }
  for (int i = tid; i < 1024; i += 256) {
    int nt = i >> 8, rem = i & 255;
    int L = rem >> 2, d = rem & 3;
    int u = nt * 16 + (L & 15);
    int p = (L >> 4) * 4 + d;
    sBr2[i] = (int)pkbf(Wr2[p * 64 + u], Wr2[(p + 16) * 64 + u]);
  }
  __syncthreads();

  float br1v[2] = {br1[l15], br1[16 + l15]};
  float br2v[4];
#pragma unroll
  for (int nt = 0; nt < 4; ++nt) br2v[nt] = br2[nt * 16 + l15];

  long gw = (long)blockIdx.x * 4 + wid;
  long nw = (long)gridDim.x * 4;
  for (long row0 = gw * 16; row0 < TBROWS; row0 += nw * 16) {
    {
      int j = lane;
      float v = x[row0 * 9 + j];
      int r = (j * 456) >> 12; int cc = j - r * 9;
      sx[wid][r * 12 + cc] = v;
      j = lane + 64;
      v = x[row0 * 9 + j];
      r = (j * 456) >> 12; cc = j - r * 9;
      sx[wid][r * 12 + cc] = v;
      if (lane < 16) {
        j = lane + 128;
        v = x[row0 * 9 + j];
        r = (j * 456) >> 12; cc = j - r * 9;
        sx[wid][r * 12 + cc] = v;
      }
    }
    float4 xq = *(const float4*)&sx[wid][l15 * 12 + g4 * 4];
    union { unsigned u[4]; bf16x8 v; } A1;
#pragma unroll
    for (int d = 0; d < 4; ++d) {
      float v = ((const float*)&xq)[d];
      v = (g4 * 4 + d < 9) ? v : 0.f;
      A1.u[d] = bfbits(v);
    }
    f32x4 c1[2];
#pragma unroll
    for (int nt = 0; nt < 2; ++nt) {
      c1[nt] = (f32x4){br1v[nt], br1v[nt], br1v[nt], br1v[nt]};
      c1[nt] = __builtin_amdgcn_mfma_f32_16x16x32_bf16(
          A1.v, *(const bf16x8*)&sBr1[nt * 256 + lane * 4], c1[nt], 0, 0, 0);
    }
#pragma unroll
    for (int r = 0; r < 4; ++r)
      h1s[wid][(g4 * 4 + r) * 20 + l15] =
          (int)pkbf(fmaxf(c1[0][r], 0.f), fmaxf(c1[1][r], 0.f));
    bf16x8 A2 = *(const bf16x8*)&h1s[wid][l15 * 20 + g4 * 4];
    f32x4 c2[4];
#pragma unroll
    for (int nt = 0; nt < 4; ++nt) {
      c2[nt] = (f32x4){br2v[nt], br2v[nt], br2v[nt], br2v[nt]};
      c2[nt] = __builtin_amdgcn_mfma_f32_16x16x32_bf16(
          A2, *(const bf16x8*)&sBr2[nt * 256 + lane * 4], c2[nt], 0, 0, 0);
    }
#pragma unroll
    for (int nt = 0; nt < 4; ++nt)
#pragma unroll
      for (int r = 0; r < 4; ++r)
        hb[(row0 + g4 * 4 + r) * 64 + nt * 16 + l15] =
            (unsigned short)bfbits(fmaxf(c2[nt][r], 0.f));
  }
}

// ---------------- k2m: MFMA serial LSTM ----------------
// C layout (m89): col = lane&15, row = (lane>>4)*4 + reg.
// Gate wave w: nt = g*4+w -> unit j = 16w + (lane&15), gate g.
__global__ __launch_bounds__(320) void k2m(
    const unsigned short* __restrict__ hb, const int* __restrict__ done,
    const float* __restrict__ h0, const float* __restrict__ c0,
    const float* __restrict__ Wih, const float* __restrict__ Whh,
    const float* __restrict__ bl,
    const float* __restrict__ Wc1, const float* __restrict__ bc1,
    const float* __restrict__ Wc2, const float* __restrict__ bc2,
    const float* __restrict__ Wc3, const float* __restrict__ bc3,
    float* __restrict__ out) {
  __shared__ __align__(16) unsigned short hT2[2][16 * 72];  // double-buffered h (unmasked)
  __shared__ float sv1[16 * 20];                            // critic v1 bounce
  __shared__ __align__(16) float smask[TT * 16];            // 1 - done (float, for c mask)
  __shared__ int sdn[TT * 16];                              // done flags (for h cndmask)

  const int tid = threadIdx.x;
  const int lane = tid & 63;
  const int wid = tid >> 6;
  const int g4 = lane >> 4, l15 = lane & 15;
  const int base_b = blockIdx.x * 16;

  for (int i = tid; i < TT * 16; i += 320) {
    int d = done[(long)(i >> 4) * BB + base_b + (i & 15)];
    sdn[i] = d;
    smask[i] = 1.f - (float)d;
  }

  union frag { unsigned u[4]; bf16x8 v; };
  frag Bih[4][2], Bhh[4][2];
  frag Bc1[2];
  float wc2a[16], wc2b[16];
  float c[4];
  f32x4 bias_acc[4];  // persistent splatted bias (MFMA C-input, never overwritten)
  float bc1s = 0.f, bc2s0 = 0.f, bc2s1 = 0.f, wc3a = 0.f, wc3b = 0.f, bc3r = 0.f;

  if (wid < 4) {
#pragma unroll
    for (int g = 0; g < 4; ++g) {
      int nt = g * 4 + wid;
      int col = nt * 16 + l15;
      float sc = (g == 2) ? 2.f * LOG2E : LOG2E;
#pragma unroll
      for (int q = 0; q < 2; ++q)
#pragma unroll
        for (int d = 0; d < 4; ++d) {
          int k0 = q * 32 + g4 * 8 + 2 * d;
          Bih[g][q].u[d] = pkbf(Wih[k0 * 256 + col] * sc, Wih[(k0 + 1) * 256 + col] * sc);
          Bhh[g][q].u[d] = pkbf(Whh[k0 * 256 + col] * sc, Whh[(k0 + 1) * 256 + col] * sc);
        }
      float bv = bl[nt * 16 + l15] * sc;
      bias_acc[g] = (f32x4){bv, bv, bv, bv};
    }
#pragma unroll
    for (int r = 0; r < 4; ++r) {
      int row = base_b + g4 * 4 + r;
      float m0 = 1.f - (float)done[row];
      c[r] = c0[row * 64 + wid * 16 + l15] * m0;
      hT2[1][(g4 * 4 + r) * 72 + wid * 16 + l15] =
          (unsigned short)bfbits(h0[row * 64 + wid * 16 + l15]);
    }
  } else {
    float S = 2.f * LOG2E;
#pragma unroll
    for (int q = 0; q < 2; ++q)
#pragma unroll
      for (int d = 0; d < 4; ++d) {
        int k0 = q * 32 + g4 * 8 + 2 * d;
        Bc1[q].u[d] = pkbf(Wc1[k0 * 16 + l15] * S, Wc1[(k0 + 1) * 16 + l15] * S);
      }
#pragma unroll
    for (int k = 0; k < 16; ++k) {
      wc2a[k] = Wc2[k * 8 + g4 * 2] * S;
      wc2b[k] = Wc2[k * 8 + g4 * 2 + 1] * S;
    }
    bc1s = bc1[l15] * S;
    bc2s0 = bc2[g4 * 2] * S;
    bc2s1 = bc2[g4 * 2 + 1] * S;
    wc3a = Wc3[g4 * 2];
    wc3b = Wc3[g4 * 2 + 1];
    bc3r = bc3[0];
  }
  __syncthreads();  // full barrier once (setup visibility)

  // gate-wave loop state: dist-2 prefetch registers (in-place reload, no copies)
  bf16x8 aA0 = {}, aA1 = {}, aB0 = {}, aB1 = {};
  int dnA = 0, dnB = 0;
  if (wid < 4) {
    long r0a = ((long)0 * BB + base_b + l15) * 64;
    long r1a = ((long)1 * BB + base_b + l15) * 64;
    aA0 = *(const bf16x8*)(hb + r0a + g4 * 8);
    aA1 = *(const bf16x8*)(hb + r0a + 32 + g4 * 8);
    aB0 = *(const bf16x8*)(hb + r1a + g4 * 8);
    aB1 = *(const bf16x8*)(hb + r1a + 32 + g4 * 8);
    dnA = sdn[0 * 16 + l15];
    dnB = sdn[1 * 16 + l15];
  }

  auto gate_step = [&](int t, bf16x8& x0, bf16x8& x1, int& dnv) {
    const unsigned short* rb = hT2[(t + 1) & 1];  // h_{t-1}
    unsigned short* wb = hT2[t & 1];
    __builtin_amdgcn_s_setprio(1);
    // 1. issue LDS reads first (latency filled by Wih MFMAs below)
    int4 r0 = *(const int4*)(rb + l15 * 72 + g4 * 8);
    int4 r1 = *(const int4*)(rb + l15 * 72 + 32 + g4 * 8);
    int tm = (t + 1 < TT) ? t + 1 : t;
    float4 mn4 = *(const float4*)&smask[tm * 16 + g4 * 4];
    // 2. Wih MFMAs (h-independent), C-input = persistent bias regs (D != C)
    f32x4 acc[4];
#pragma unroll
    for (int g = 0; g < 4; ++g)
      acc[g] = __builtin_amdgcn_mfma_f32_16x16x32_bf16(x0, Bih[g][0].v, bias_acc[g], 0, 0, 0);
#pragma unroll
    for (int g = 0; g < 4; ++g)
      acc[g] = __builtin_amdgcn_mfma_f32_16x16x32_bf16(x1, Bih[g][1].v, acc[g], 0, 0, 0);
    // 3. mask h_{t-1}, Whh MFMAs
    if (dnv != 0) { r0 = make_int4(0, 0, 0, 0); r1 = make_int4(0, 0, 0, 0); }
    union { int4 i4; bf16x8 v; } ah0, ah1;
    ah0.i4 = r0; ah1.i4 = r1;
#pragma unroll
    for (int g = 0; g < 4; ++g)
      acc[g] = __builtin_amdgcn_mfma_f32_16x16x32_bf16(ah0.v, Bhh[g][0].v, acc[g], 0, 0, 0);
#pragma unroll
    for (int g = 0; g < 4; ++g)
      acc[g] = __builtin_amdgcn_mfma_f32_16x16x32_bf16(ah1.v, Bhh[g][1].v, acc[g], 0, 0, 0);
    // 4. in-place dist-2 reload (issue now, wait ~2 steps later)
    if (t + 2 < TT) {
      long nb = ((long)(t + 2) * BB + base_b + l15) * 64;
      x0 = *(const bf16x8*)(hb + nb + g4 * 8);
      x1 = *(const bf16x8*)(hb + nb + 32 + g4 * 8);
      dnv = sdn[(t + 2) * 16 + l15];
    }
    // 5. elementwise + h store
#pragma unroll
    for (int r = 0; r < 4; ++r) {
      float xi = acc[0][r], xf = acc[1][r], xg = acc[2][r], xo = acc[3][r];
      float si = rcpf_(1.f + exp2f_(-xi));
      float sf = rcpf_(1.f + exp2f_(-xf));
      float so = rcpf_(1.f + exp2f_(-xo));
      float tg = fmaf(2.f, rcpf_(1.f + exp2f_(-xg)), -1.f);
      float cc = fmaf(sf, c[r], si * tg);
      float tc = fmaf(2.f, rcpf_(1.f + exp2f_(cc * (-2.f * LOG2E))), -1.f);
      float oh = so * tc;
      c[r] = cc * ((const float*)&mn4)[r];  // mask for t+1
      wb[(g4 * 4 + r) * 72 + wid * 16 + l15] = cvt1bf(oh);
    }
    __builtin_amdgcn_s_setprio(0);
  };

  auto critic_step = [&](int tprev, const unsigned short* rb) {
    bf16x8 ca0 = *(const bf16x8*)(rb + l15 * 72 + g4 * 8);
    bf16x8 ca1 = *(const bf16x8*)(rb + l15 * 72 + 32 + g4 * 8);
    f32x4 a1 = (f32x4){bc1s, bc1s, bc1s, bc1s};
    a1 = __builtin_amdgcn_mfma_f32_16x16x32_bf16(ca0, Bc1[0].v, a1, 0, 0, 0);
    a1 = __builtin_amdgcn_mfma_f32_16x16x32_bf16(ca1, Bc1[1].v, a1, 0, 0, 0);
#pragma unroll
    for (int r = 0; r < 4; ++r) {
      float v1 = fmaf(2.f, rcpf_(1.f + exp2f_(-a1[r])), -1.f);
      sv1[(g4 * 4 + r) * 20 + l15] = v1;
    }
    float a2a = bc2s0, a2b = bc2s1;
    const float* vrow = &sv1[l15 * 20];
#pragma unroll
    for (int k = 0; k < 16; ++k) {
      float vk = vrow[k];
      a2a = fmaf(vk, wc2a[k], a2a);
      a2b = fmaf(vk, wc2b[k], a2b);
    }
    float v2a = fmaf(2.f, rcpf_(1.f + exp2f_(-a2a)), -1.f);
    float v2b = fmaf(2.f, rcpf_(1.f + exp2f_(-a2b)), -1.f);
    float p = fmaf(v2a, wc3a, v2b * wc3b);
    p += __shfl_xor(p, 16);
    p += __shfl_xor(p, 32);
    if (g4 == 0) out[(long)tprev * BB + base_b + l15] = p + bc3r;
  };

  for (int t2 = 0; t2 < TT; t2 += 2) {
    // ---- even sub-step t = t2 ----
    if (wid < 4) {
      gate_step(t2, aA0, aA1, dnA);
    } else {
      if (t2 > 0) critic_step(t2 - 1, hT2[(t2 + 1) & 1]);
    }
    BAR_LDS();
    // ---- odd sub-step t = t2+1 ----
    if (wid < 4) {
      gate_step(t2 + 1, aB0, aB1, dnB);
    } else {
      critic_step(t2, hT2[(t2 + 2) & 1]);
    }
    BAR_LDS();
  }
  if (wid == 4) critic_step(TT - 1, hT2[(TT - 1) & 1]);
}

extern "C" void kernel_launch(void* const* d_in, const int* in_sizes, int n_in,
                              void* d_out, int out_size, void* d_ws, size_t ws_size,
                              hipStream_t stream) {
  const float* x = (const float*)d_in[0];
  const int* done = (const int*)d_in[1];
  const float* h0 = (const float*)d_in[2];
  const float* c0 = (const float*)d_in[3];
  const float* Wr1 = (const float*)d_in[4];
  const float* br1 = (const float*)d_in[5];
  const float* Wr2 = (const float*)d_in[6];
  const float* br2 = (const float*)d_in[7];
  const float* Wih = (const float*)d_in[8];
  const float* Whh = (const float*)d_in[9];
  const float* bl = (const float*)d_in[10];
  const float* Wc1 = (const float*)d_in[11];
  const float* bc1 = (const float*)d_in[12];
  const float* Wc2 = (const float*)d_in[13];
  const float* bc2 = (const float*)d_in[14];
  const float* Wc3 = (const float*)d_in[15];
  const float* bc3 = (const float*)d_in[16];
  float* out = (float*)d_out;

  unsigned short* hb = (unsigned short*)d_ws;  // 128 MB bf16 hid (read-only after k1m)

  k1m<<<dim3(1024), dim3(256), 0, stream>>>(x, Wr1, br1, Wr2, br2, hb);
  k2m<<<dim3(256), dim3(320), 0, stream>>>(hb, done, h0, c0, Wih, Whh, bl,
                                           Wc1, bc1, Wc2, bc2, Wc3, bc3, out);
}